// Round 1
// baseline (385.804 us; speedup 1.0000x reference)
//
#include <hip/hip_runtime.h>
#include <math.h>

#define Bn 32
#define Cn 64
#define Ln 2048
#define NFREQ 1025
#define S0c 341
#define S1c 341
#define S2c 343

#define PI_D 3.14159265358979323846

// ---------------- K1: twiddle table ----------------
__global__ void k_twiddle(double2* __restrict__ tw) {
    int t = blockIdx.x * blockDim.x + threadIdx.x;
    if (t < 1024) {
        double ang = -2.0 * PI_D * (double)t / 2048.0;
        double s, c;
        sincos(ang, &s, &c);
        tw[t] = make_double2(c, s);
    }
}

// ---------------- K2: radix-2 DIF FFT (len 2048), |rfft| -> f32 ----------------
__global__ __launch_bounds__(256) void k_fft(const float* __restrict__ X,
                                             const double2* __restrict__ tw,
                                             float* __restrict__ XF) {
    __shared__ double re[2048];
    __shared__ double im[2048];
    int row = blockIdx.x;           // b*C + c, 2048 rows
    int tid = threadIdx.x;
    const float* xr = X + (size_t)row * Ln;
    for (int t = tid; t < 2048; t += 256) { re[t] = (double)xr[t]; im[t] = 0.0; }
    __syncthreads();
    // DIF: natural input, bit-reversed output. X[f] lands at bitrev11(f).
    for (int log2h = 10; log2h >= 0; --log2h) {
        int half = 1 << log2h;
        #pragma unroll
        for (int bfi = 0; bfi < 4; ++bfi) {
            int bf = tid + bfi * 256;           // 1024 butterflies/stage
            int k  = bf & (half - 1);
            int g  = bf >> log2h;
            int i1 = (g << (log2h + 1)) + k;
            int i2 = i1 + half;
            double ar = re[i1], ai = im[i1];
            double br = re[i2], bi = im[i2];
            double2 w = tw[k << (10 - log2h)];
            re[i1] = ar + br; im[i1] = ai + bi;
            double tr = ar - br, ti = ai - bi;
            re[i2] = tr * w.x - ti * w.y;
            im[i2] = tr * w.y + ti * w.x;
        }
        __syncthreads();
    }
    float* out = XF + (size_t)row * NFREQ;
    for (int f = tid; f < NFREQ; f += 256) {
        int rv = (int)(__brev((unsigned)f) >> 21);   // bitrev over 11 bits
        double a = re[rv], b = im[rv];
        out[f] = (float)sqrt(a * a + b * b);
    }
}

// ---------------- K3: Y = band @ A^T  (per band), f64 accumulate ----------------
// Y[(bc), O+d] = sum_s A[d*S+s] * XF[(bc)*NFREQ + O + s]
__global__ __launch_bounds__(256) void k_gemm(const float* __restrict__ XF,
                                              const float* __restrict__ A,
                                              double* __restrict__ Y,
                                              int S, int O) {
    __shared__ float sX[64][33];   // [bc][s]
    __shared__ float sA[32][65];   // [s][d]
    int bc0 = blockIdx.x * 64;
    int d0  = blockIdx.y * 64;
    int tid = threadIdx.x;
    int tx = tid & 15, ty = tid >> 4;
    double acc[4][4] = {};
    for (int s0 = 0; s0 < S; s0 += 32) {
        for (int e = tid; e < 2048; e += 256) {
            int r = e >> 5, cc = e & 31;
            int s = s0 + cc;
            sX[r][cc] = (s < S) ? XF[(size_t)(bc0 + r) * NFREQ + O + s] : 0.0f;
        }
        for (int e = tid; e < 2048; e += 256) {
            int r = e >> 5, cc = e & 31;       // r: d idx, cc: s idx
            int d = d0 + r, s = s0 + cc;
            sA[cc][r] = (d < S && s < S) ? A[(size_t)d * S + s] : 0.0f;
        }
        __syncthreads();
        #pragma unroll
        for (int kk = 0; kk < 32; ++kk) {
            float xv[4], av[4];
            #pragma unroll
            for (int i = 0; i < 4; ++i) xv[i] = sX[ty * 4 + i][kk];
            #pragma unroll
            for (int j = 0; j < 4; ++j) av[j] = sA[kk][tx * 4 + j];
            #pragma unroll
            for (int i = 0; i < 4; ++i)
                #pragma unroll
                for (int j = 0; j < 4; ++j)
                    acc[i][j] = fma((double)xv[i], (double)av[j], acc[i][j]);
        }
        __syncthreads();
    }
    for (int i = 0; i < 4; ++i) {
        int bc = bc0 + ty * 4 + i;
        for (int j = 0; j < 4; ++j) {
            int d = d0 + tx * 4 + j;
            if (d < S) Y[(size_t)bc * NFREQ + O + d] = acc[i][j];
        }
    }
}

// ---------------- K4: pairwise sq-distances, band-weighted fuse ----------------
// block = (b, 16x16 pair tile). dist[b,i,j] = sum_k w_k * |Y_i - Y_j|^2 (band k)
__global__ __launch_bounds__(256) void k_dist(const double* __restrict__ Y,
                                              const float* __restrict__ fw,
                                              double* __restrict__ dist) {
    __shared__ double sYi[16][129];
    __shared__ double sYj[16][129];
    int b = blockIdx.x;
    int q = blockIdx.y;
    int qi = q >> 2, qj = q & 3;
    int tid = threadIdx.x;
    int tx = tid & 15, ty = tid >> 4;

    double f0 = (double)fw[0], f1 = (double)fw[1], f2 = (double)fw[2];
    double m = fmax(f0, fmax(f1, f2));
    double e0 = exp(f0 - m), e1 = exp(f1 - m), e2 = exp(f2 - m);
    double esum = e0 + e1 + e2;
    double w[3] = { e0 / esum, e1 / esum, e2 / esum };
    int bandStart[3] = {0, S0c, S0c + S1c};
    int bandEnd[3]   = {S0c, S0c + S1c, NFREQ};

    const double* Yb = Y + (size_t)b * Cn * NFREQ;
    double fused = 0.0;
    for (int k = 0; k < 3; ++k) {
        double acc = 0.0;
        int endk = bandEnd[k];
        for (int d0 = bandStart[k]; d0 < endk; d0 += 128) {
            for (int e = tid; e < 16 * 128; e += 256) {
                int r = e >> 7, cc = e & 127;
                int d = d0 + cc;
                sYi[r][cc] = (d < endk) ? Yb[(size_t)(qi * 16 + r) * NFREQ + d] : 0.0;
                sYj[r][cc] = (d < endk) ? Yb[(size_t)(qj * 16 + r) * NFREQ + d] : 0.0;
            }
            __syncthreads();
            #pragma unroll 8
            for (int cc = 0; cc < 128; ++cc) {
                double diff = sYi[ty][cc] - sYj[tx][cc];
                acc = fma(diff, diff, acc);
            }
            __syncthreads();
        }
        fused += w[k] * fmax(acc, 0.0);
    }
    int i = qi * 16 + ty, j = qj * 16 + tx;
    dist[(size_t)b * 4096 + i * 64 + j] = fused;
}

// ---------------- K5: row max + gumbel decision ----------------
__global__ __launch_bounds__(256) void k_decide(const double* __restrict__ dist,
                                                const float* __restrict__ gum,
                                                float* __restrict__ out) {
    __shared__ double sD[4096];
    __shared__ double sEmax[64];
    int b = blockIdx.x;
    int tid = threadIdx.x;
    const double* db = dist + (size_t)b * 4096;
    for (int e = tid; e < 4096; e += 256) sD[e] = db[e];
    __syncthreads();
    if (tid < 64) {
        int i = tid;
        double emax = 0.0;
        for (int j = 0; j < 64; ++j) {
            if (j == i) continue;
            double e = 1.0 / (sD[i * 64 + j] + 1e-10);
            emax = fmax(emax, e);
        }
        sEmax[i] = emax;
    }
    __syncthreads();
    const float* gb = gum + (size_t)b * 4096 * 2;
    float* ob = out + (size_t)b * 4096;
    for (int idx = tid; idx < 4096; idx += 256) {
        int i = idx >> 6, j = idx & 63;
        double p;
        if (i == j) {
            p = 0.99;
        } else {
            double e = 1.0 / (sD[idx] + 1e-10);
            p = (e / sEmax[i]) * 0.99;
        }
        double l0 = log(p / (1.0 - p));
        double l1 = log((1.0 - p) / p);
        double y0 = l0 + (double)gb[idx * 2 + 0];
        double y1 = l1 + (double)gb[idx * 2 + 1];
        // argmax over {y0,y1}, first index wins ties; straight-through value
        // is numerically exactly the one-hot -> output exact 0/1.
        ob[idx] = (y0 >= y1) ? 1.0f : 0.0f;
    }
}

// ---------------- launcher ----------------
extern "C" void kernel_launch(void* const* d_in, const int* in_sizes, int n_in,
                              void* d_out, int out_size, void* d_ws, size_t ws_size,
                              hipStream_t stream) {
    const float* X  = (const float*)d_in[0];
    const float* A0 = (const float*)d_in[1];
    const float* A1 = (const float*)d_in[2];
    const float* A2 = (const float*)d_in[3];
    const float* fw = (const float*)d_in[4];
    const float* gm = (const float*)d_in[5];
    float* out = (float*)d_out;

    char* ws = (char*)d_ws;
    double2* tw  = (double2*)(ws);                         // 16 KB
    float*   XF  = (float*)(ws + 16384);                   // 2048*1025*4 = 8,396,800 B
    double*  Y   = (double*)(ws + 8413184);                // 2048*1025*8 = 16,793,600 B
    double*  dst = (double*)(ws + 25206784);               // 32*4096*8  = 1,048,576 B

    k_twiddle<<<4, 256, 0, stream>>>(tw);
    k_fft<<<Bn * Cn, 256, 0, stream>>>(X, tw, XF);
    k_gemm<<<dim3(32, 6), 256, 0, stream>>>(XF, A0, Y, S0c, 0);
    k_gemm<<<dim3(32, 6), 256, 0, stream>>>(XF, A1, Y, S1c, S0c);
    k_gemm<<<dim3(32, 6), 256, 0, stream>>>(XF, A2, Y, S2c, S0c + S1c);
    k_dist<<<dim3(Bn, 16), 256, 0, stream>>>(Y, fw, dst);
    k_decide<<<Bn, 256, 0, stream>>>(dst, gm, out);
}

// Round 2
// 262.003 us; speedup vs baseline: 1.4725x; 1.4725x over previous
//
#include <hip/hip_runtime.h>
#include <math.h>

#define Bn 32
#define Cn 64
#define Ln 2048
#define NFREQ 1025
#define S0c 341
#define S1c 341
#define S2c 343

#define PI_D 3.14159265358979323846

// ---------------- K1: twiddle table ----------------
__global__ void k_twiddle(double2* __restrict__ tw) {
    int t = blockIdx.x * blockDim.x + threadIdx.x;
    if (t < 1024) {
        double ang = -2.0 * PI_D * (double)t / 2048.0;
        double s, c;
        sincos(ang, &s, &c);
        tw[t] = make_double2(c, s);
    }
}

// ---------------- K2: radix-2 DIF FFT (len 2048), |rfft| -> f32 ----------------
__global__ __launch_bounds__(256) void k_fft(const float* __restrict__ X,
                                             const double2* __restrict__ tw,
                                             float* __restrict__ XF) {
    __shared__ double re[2048];
    __shared__ double im[2048];
    int row = blockIdx.x;           // b*C + c, 2048 rows
    int tid = threadIdx.x;
    const float* xr = X + (size_t)row * Ln;
    for (int t = tid; t < 2048; t += 256) { re[t] = (double)xr[t]; im[t] = 0.0; }
    __syncthreads();
    // DIF: natural input, bit-reversed output. X[f] lands at bitrev11(f).
    for (int log2h = 10; log2h >= 0; --log2h) {
        int half = 1 << log2h;
        #pragma unroll
        for (int bfi = 0; bfi < 4; ++bfi) {
            int bf = tid + bfi * 256;           // 1024 butterflies/stage
            int k  = bf & (half - 1);
            int g  = bf >> log2h;
            int i1 = (g << (log2h + 1)) + k;
            int i2 = i1 + half;
            double ar = re[i1], ai = im[i1];
            double br = re[i2], bi = im[i2];
            double2 w = tw[k << (10 - log2h)];
            re[i1] = ar + br; im[i1] = ai + bi;
            double tr = ar - br, ti = ai - bi;
            re[i2] = tr * w.x - ti * w.y;
            im[i2] = tr * w.y + ti * w.x;
        }
        __syncthreads();
    }
    float* out = XF + (size_t)row * NFREQ;
    for (int f = tid; f < NFREQ; f += 256) {
        int rv = (int)(__brev((unsigned)f) >> 21);   // bitrev over 11 bits
        double a = re[rv], b = im[rv];
        out[f] = (float)sqrt(a * a + b * b);
    }
}

// ---------------- K3: fused 3-band GEMM, Y = band @ A^T, f64 accumulate ----------------
// grid (32 row-tiles, 6 col-tiles, 3 bands); block 256; 64x64 tile, BK=16.
// Y[(bc), O+d] = sum_s A[d*S+s] * XF[(bc)*NFREQ + O + s]
__global__ __launch_bounds__(256) void k_gemm(const float* __restrict__ XF,
                                              const float* __restrict__ A0,
                                              const float* __restrict__ A1,
                                              const float* __restrict__ A2,
                                              double* __restrict__ Y) {
    const int Sarr[3] = {S0c, S1c, S2c};
    const int Oarr[3] = {0, S0c, S0c + S1c};
    int z = blockIdx.z;
    const float* A = (z == 0) ? A0 : ((z == 1) ? A1 : A2);
    int S = Sarr[z], O = Oarr[z];

    __shared__ float sXT[16][68];   // [s_local][row]  stride 68 -> 16B-aligned rows
    __shared__ float sA [16][68];   // [s_local][d]
    int bc0 = blockIdx.x * 64;
    int d0  = blockIdx.y * 64;
    int tid = threadIdx.x;
    int tx = tid & 15, ty = tid >> 4;
    int sl = tid & 15;              // staging: s-local (coalesced global reads)
    int rb = (tid >> 4) * 4;        // staging: row/col base

    double acc[4][4] = {};
    for (int s0 = 0; s0 < S; s0 += 16) {
        int s = s0 + sl;
        bool sv = (s < S);
        #pragma unroll
        for (int i = 0; i < 4; ++i) {
            sXT[sl][rb + i] = sv ? XF[(size_t)(bc0 + rb + i) * NFREQ + O + s] : 0.0f;
            int d = d0 + rb + i;
            sA[sl][rb + i] = (sv && d < S) ? A[(size_t)d * S + s] : 0.0f;
        }
        __syncthreads();
        #pragma unroll
        for (int kk = 0; kk < 16; ++kk) {
            float4 x4 = *(const float4*)&sXT[kk][ty * 4];
            float4 a4 = *(const float4*)&sA[kk][tx * 4];
            double xd[4] = {(double)x4.x, (double)x4.y, (double)x4.z, (double)x4.w};
            double ad[4] = {(double)a4.x, (double)a4.y, (double)a4.z, (double)a4.w};
            #pragma unroll
            for (int i = 0; i < 4; ++i)
                #pragma unroll
                for (int j = 0; j < 4; ++j)
                    acc[i][j] = fma(xd[i], ad[j], acc[i][j]);
        }
        __syncthreads();
    }
    #pragma unroll
    for (int i = 0; i < 4; ++i) {
        int bc = bc0 + ty * 4 + i;
        #pragma unroll
        for (int j = 0; j < 4; ++j) {
            int d = d0 + tx * 4 + j;
            if (d < S) Y[(size_t)bc * NFREQ + O + d] = acc[i][j];
        }
    }
}

// ---------------- K4: pairwise weighted sq-distance partials ----------------
// grid (32 batches, 8 dim-chunks); block 256. Each block: full 64x64 pair tile
// over ~128 dims, pre-scaled by sqrt(w_band). part[b][chunk][i][j].
__global__ __launch_bounds__(256) void k_dist(const double* __restrict__ Y,
                                              const float* __restrict__ fw,
                                              double* __restrict__ part) {
    __shared__ double sY[64][65];   // [row][dim-local], stride 65 (conflict-free reads)
    int b = blockIdx.x;
    int chunk = blockIdx.y;
    int dlo = chunk * 128;
    int dhi = (chunk == 7) ? NFREQ : dlo + 128;
    int tid = threadIdx.x;
    int tx = tid & 15, ty = tid >> 4;

    double f0 = (double)fw[0], f1 = (double)fw[1], f2 = (double)fw[2];
    double m = fmax(f0, fmax(f1, f2));
    double e0 = exp(f0 - m), e1 = exp(f1 - m), e2 = exp(f2 - m);
    double esum = e0 + e1 + e2;
    double sw0 = sqrt(e0 / esum), sw1 = sqrt(e1 / esum), sw2 = sqrt(e2 / esum);

    const double* Yb = Y + (size_t)b * Cn * NFREQ;
    double acc[4][4] = {};
    for (int d0 = dlo; d0 < dhi; d0 += 64) {
        for (int e = tid; e < 64 * 64; e += 256) {
            int r = e >> 6, c = e & 63;
            int d = d0 + c;
            double v = 0.0;
            if (d < dhi) {
                double sw = (d < S0c) ? sw0 : ((d < S0c + S1c) ? sw1 : sw2);
                v = Yb[(size_t)r * NFREQ + d] * sw;
            }
            sY[r][c] = v;
        }
        __syncthreads();
        #pragma unroll 4
        for (int kk = 0; kk < 64; ++kk) {
            double yi[4], yj[4];
            #pragma unroll
            for (int ii = 0; ii < 4; ++ii) yi[ii] = sY[16 * ii + ty][kk];
            #pragma unroll
            for (int jj = 0; jj < 4; ++jj) yj[jj] = sY[16 * jj + tx][kk];
            #pragma unroll
            for (int ii = 0; ii < 4; ++ii)
                #pragma unroll
                for (int jj = 0; jj < 4; ++jj) {
                    double diff = yi[ii] - yj[jj];
                    acc[ii][jj] = fma(diff, diff, acc[ii][jj]);
                }
        }
        __syncthreads();
    }
    double* pb = part + (((size_t)b * 8 + chunk) << 12);
    #pragma unroll
    for (int ii = 0; ii < 4; ++ii)
        #pragma unroll
        for (int jj = 0; jj < 4; ++jj)
            pb[(16 * ii + ty) * 64 + (16 * jj + tx)] = acc[ii][jj];
}

// ---------------- K5: sum partials, row max, gumbel decision ----------------
__global__ __launch_bounds__(256) void k_decide(const double* __restrict__ part,
                                                const float* __restrict__ gum,
                                                float* __restrict__ out) {
    __shared__ double sD[4096];
    __shared__ double sEmax[64];
    int b = blockIdx.x;
    int tid = threadIdx.x;
    for (int idx = tid; idx < 4096; idx += 256) {
        double s = 0.0;
        #pragma unroll
        for (int c = 0; c < 8; ++c)
            s += part[(((size_t)b * 8 + c) << 12) + idx];
        sD[idx] = s;
    }
    __syncthreads();
    if (tid < 64) {
        int i = tid;
        double emax = 0.0;
        for (int j = 0; j < 64; ++j) {
            if (j == i) continue;
            double e = 1.0 / (sD[i * 64 + j] + 1e-10);
            emax = fmax(emax, e);
        }
        sEmax[i] = emax;
    }
    __syncthreads();
    const float* gb = gum + (size_t)b * 4096 * 2;
    float* ob = out + (size_t)b * 4096;
    for (int idx = tid; idx < 4096; idx += 256) {
        int i = idx >> 6;
        double p;
        if (i == (idx & 63)) {
            p = 0.99;
        } else {
            double e = 1.0 / (sD[idx] + 1e-10);
            p = (e / sEmax[i]) * 0.99;
        }
        double l0 = log(p / (1.0 - p));
        double l1 = log((1.0 - p) / p);
        double y0 = l0 + (double)gb[idx * 2 + 0];
        double y1 = l1 + (double)gb[idx * 2 + 1];
        // straight-through value is numerically exactly the one-hot -> 0/1.
        ob[idx] = (y0 >= y1) ? 1.0f : 0.0f;
    }
}

// ---------------- launcher ----------------
extern "C" void kernel_launch(void* const* d_in, const int* in_sizes, int n_in,
                              void* d_out, int out_size, void* d_ws, size_t ws_size,
                              hipStream_t stream) {
    const float* X  = (const float*)d_in[0];
    const float* A0 = (const float*)d_in[1];
    const float* A1 = (const float*)d_in[2];
    const float* A2 = (const float*)d_in[3];
    const float* fw = (const float*)d_in[4];
    const float* gm = (const float*)d_in[5];
    float* out = (float*)d_out;

    char* ws = (char*)d_ws;
    double2* tw  = (double2*)(ws);                 // 16 KB
    float*   XF  = (float*)(ws + 16384);           // 2048*1025*4 = 8,396,800 B
    double*  Y   = (double*)(ws + 8413184);        // 2048*1025*8 = 16,793,600 B
    // part aliases XF (dead after gemm): 32*8*4096*8 = 8,388,608 B <= 8,396,800 B
    double*  part = (double*)(ws + 16384);

    k_twiddle<<<4, 256, 0, stream>>>(tw);
    k_fft<<<Bn * Cn, 256, 0, stream>>>(X, tw, XF);
    k_gemm<<<dim3(32, 6, 3), 256, 0, stream>>>(XF, A0, A1, A2, Y);
    k_dist<<<dim3(Bn, 8), 256, 0, stream>>>(Y, fw, part);
    k_decide<<<Bn, 256, 0, stream>>>(part, gm, out);
}

// Round 3
// 217.337 us; speedup vs baseline: 1.7751x; 1.2055x over previous
//
#include <hip/hip_runtime.h>
#include <math.h>

#define Bn 32
#define Cn 64
#define Ln 2048
#define NFREQ 1025
#define S0c 341
#define S1c 341
#define S2c 343

#define PI_D 3.14159265358979323846

// ---------------- K1: twiddle table tw[t] = e^{-2 pi i t / 2048}, t<1024 ----------------
__global__ void k_twiddle(double2* __restrict__ tw) {
    int t = blockIdx.x * blockDim.x + threadIdx.x;
    if (t < 1024) {
        double ang = -2.0 * PI_D * (double)t / 2048.0;
        double s, c;
        sincos(ang, &s, &c);
        tw[t] = make_double2(c, s);
    }
}

// ---------------- K2: packed-real rfft via 1024-pt complex FFT + split ----------------
__global__ __launch_bounds__(256) void k_fft(const float* __restrict__ X,
                                             const double2* __restrict__ tw,
                                             float* __restrict__ XF) {
    __shared__ double re[1024];
    __shared__ double im[1024];
    int row = blockIdx.x;
    int tid = threadIdx.x;
    const float2* xr = (const float2*)(X + (size_t)row * Ln);
    for (int m = tid; m < 1024; m += 256) {
        float2 v = xr[m];
        re[m] = (double)v.x; im[m] = (double)v.y;   // z[m] = x[2m] + i x[2m+1]
    }
    __syncthreads();
    // DIF radix-2, M=1024: natural in, bit-reversed out (10 bits)
    for (int log2h = 9; log2h >= 0; --log2h) {
        int half = 1 << log2h;
        #pragma unroll
        for (int bfi = 0; bfi < 2; ++bfi) {
            int bf = tid + bfi * 256;            // 512 butterflies/stage
            int k  = bf & (half - 1);
            int g  = bf >> log2h;
            int i1 = (g << (log2h + 1)) + k;
            int i2 = i1 + half;
            double ar = re[i1], ai = im[i1];
            double br = re[i2], bi = im[i2];
            double2 w = tw[k << (10 - log2h)];   // e^{-2pi i k/(2*half)}
            re[i1] = ar + br; im[i1] = ai + bi;
            double tr = ar - br, ti = ai - bi;
            re[i2] = tr * w.x - ti * w.y;
            im[i2] = tr * w.y + ti * w.x;
        }
        __syncthreads();
    }
    // split: X[k] = 0.5(Z_k + conj(Z_{M-k})) - 0.5 i e^{-2pi i k/2048}(Z_k - conj(Z_{M-k}))
    float* out = XF + (size_t)row * NFREQ;
    for (int k = tid; k <= 1024; k += 256) {
        double Xr, Xi;
        if (k == 0)        { Xr = re[0] + im[0]; Xi = 0.0; }
        else if (k == 1024){ Xr = re[0] - im[0]; Xi = 0.0; }
        else {
            int rv  = (int)(__brev((unsigned)k) >> 22);
            int rv2 = (int)(__brev((unsigned)(1024 - k)) >> 22);
            double Zr = re[rv],  Zi = im[rv];
            double Wr = re[rv2], Wi = im[rv2];
            double Er = 0.5 * (Zr + Wr), Ei = 0.5 * (Zi - Wi);
            double Or = 0.5 * (Zi + Wi), Oi = -0.5 * (Zr - Wr);
            double2 t = tw[k];
            Xr = Er + t.x * Or - t.y * Oi;
            Xi = Ei + t.x * Oi + t.y * Or;
        }
        out[k] = (float)sqrt(Xr * Xr + Xi * Xi);
    }
}

// ---------------- K3: fused 3-band GEMM, f64 LDS, reg-prefetch pipeline ----------------
// grid (64 row-tiles x32, 6 col-tiles x64, 3 bands); block 256; micro 4x2.
__global__ __launch_bounds__(256) void k_gemm(const float* __restrict__ XF,
                                              const float* __restrict__ A0,
                                              const float* __restrict__ A1,
                                              const float* __restrict__ A2,
                                              double* __restrict__ Y) {
    const int Sarr[3] = {S0c, S1c, S2c};
    const int Oarr[3] = {0, S0c, S0c + S1c};
    int z = blockIdx.z;
    const float* A = (z == 0) ? A0 : ((z == 1) ? A1 : A2);
    int S = Sarr[z], O = Oarr[z];

    __shared__ alignas(16) double sX[32][34];   // [k][row]  272B rows: 16B-aligned
    __shared__ alignas(16) double sA[32][66];   // [k][col]  528B rows: 16B-aligned
    int r0 = blockIdx.x * 32;
    int d0 = blockIdx.y * 64;
    int tid = threadIdx.x;
    int tx = tid & 31, ty = tid >> 5;   // cols 2tx..2tx+1, rows 4ty..4ty+3
    int kl = tid & 31;                  // staging: k-local (coalesced)
    int rl = tid >> 5;                  // staging: row/col base, stride 8

    auto load_tile = [&](int s0, float* px, float* pa) {
        int ss = s0 + kl;
        bool sv = ss < S;
        #pragma unroll
        for (int i = 0; i < 4; ++i)
            px[i] = sv ? XF[(size_t)(r0 + rl + 8 * i) * NFREQ + O + ss] : 0.0f;
        #pragma unroll
        for (int j = 0; j < 8; ++j) {
            int d = d0 + rl + 8 * j;
            pa[j] = (sv && d < S) ? A[(size_t)d * S + ss] : 0.0f;
        }
    };

    double acc[4][2] = {};
    float px[4], pa[8];
    load_tile(0, px, pa);
    int nsteps = (S + 31) / 32;
    for (int st = 0; st < nsteps; ++st) {
        __syncthreads();
        #pragma unroll
        for (int i = 0; i < 4; ++i) sX[kl][rl + 8 * i] = (double)px[i];
        #pragma unroll
        for (int j = 0; j < 8; ++j) sA[kl][rl + 8 * j] = (double)pa[j];
        __syncthreads();
        if (st + 1 < nsteps) load_tile((st + 1) * 32, px, pa);
        #pragma unroll
        for (int kk = 0; kk < 32; ++kk) {
            double2 x01 = *(const double2*)&sX[kk][4 * ty];
            double2 x23 = *(const double2*)&sX[kk][4 * ty + 2];
            double2 a01 = *(const double2*)&sA[kk][2 * tx];
            acc[0][0] = fma(x01.x, a01.x, acc[0][0]);
            acc[0][1] = fma(x01.x, a01.y, acc[0][1]);
            acc[1][0] = fma(x01.y, a01.x, acc[1][0]);
            acc[1][1] = fma(x01.y, a01.y, acc[1][1]);
            acc[2][0] = fma(x23.x, a01.x, acc[2][0]);
            acc[2][1] = fma(x23.x, a01.y, acc[2][1]);
            acc[3][0] = fma(x23.y, a01.x, acc[3][0]);
            acc[3][1] = fma(x23.y, a01.y, acc[3][1]);
        }
    }
    #pragma unroll
    for (int i = 0; i < 4; ++i) {
        int bc = r0 + 4 * ty + i;
        #pragma unroll
        for (int j = 0; j < 2; ++j) {
            int d = d0 + 2 * tx + j;
            if (d < S) Y[(size_t)bc * NFREQ + O + d] = acc[i][j];
        }
    }
}

// ---------------- K4: weighted Gram partials G = Yw Yw^T per (batch, dim-chunk) ----------------
__global__ __launch_bounds__(256) void k_dist(const double* __restrict__ Y,
                                              const float* __restrict__ fw,
                                              double* __restrict__ part) {
    __shared__ double sY[64][65];
    int b = blockIdx.x;
    int chunk = blockIdx.y;
    int dlo = chunk * 128;
    int dhi = (chunk == 7) ? NFREQ : dlo + 128;
    int tid = threadIdx.x;
    int tx = tid & 15, ty = tid >> 4;

    double f0 = (double)fw[0], f1 = (double)fw[1], f2 = (double)fw[2];
    double m = fmax(f0, fmax(f1, f2));
    double e0 = exp(f0 - m), e1 = exp(f1 - m), e2 = exp(f2 - m);
    double esum = e0 + e1 + e2;
    double sw0 = sqrt(e0 / esum), sw1 = sqrt(e1 / esum), sw2 = sqrt(e2 / esum);

    const double* Yb = Y + (size_t)b * Cn * NFREQ;
    double acc[4][4] = {};
    for (int d0 = dlo; d0 < dhi; d0 += 64) {
        for (int e = tid; e < 64 * 64; e += 256) {
            int r = e >> 6, c = e & 63;
            int d = d0 + c;
            double v = 0.0;
            if (d < dhi) {
                double sw = (d < S0c) ? sw0 : ((d < S0c + S1c) ? sw1 : sw2);
                v = Yb[(size_t)r * NFREQ + d] * sw;
            }
            sY[r][c] = v;
        }
        __syncthreads();
        #pragma unroll 8
        for (int kk = 0; kk < 64; ++kk) {
            double yi[4], yj[4];
            #pragma unroll
            for (int ii = 0; ii < 4; ++ii) yi[ii] = sY[16 * ii + ty][kk];
            #pragma unroll
            for (int jj = 0; jj < 4; ++jj) yj[jj] = sY[16 * jj + tx][kk];
            #pragma unroll
            for (int ii = 0; ii < 4; ++ii)
                #pragma unroll
                for (int jj = 0; jj < 4; ++jj)
                    acc[ii][jj] = fma(yi[ii], yj[jj], acc[ii][jj]);
        }
        __syncthreads();
    }
    double* pb = part + (((size_t)b * 8 + chunk) << 12);
    #pragma unroll
    for (int ii = 0; ii < 4; ++ii)
        #pragma unroll
        for (int jj = 0; jj < 4; ++jj)
            pb[(16 * ii + ty) * 64 + (16 * jj + tx)] = acc[ii][jj];
}

// ---------------- K5: sum Gram partials, dist = Gii+Gjj-2Gij, gumbel decision ----------------
__global__ __launch_bounds__(256) void k_decide(const double* __restrict__ part,
                                                const float* __restrict__ gum,
                                                float* __restrict__ out) {
    __shared__ double sG[4096];
    __shared__ double sQ[64];
    __shared__ double sEmax[64];
    int b = blockIdx.x;
    int tid = threadIdx.x;
    for (int idx = tid; idx < 4096; idx += 256) {
        double s = 0.0;
        #pragma unroll
        for (int c = 0; c < 8; ++c)
            s += part[(((size_t)b * 8 + c) << 12) + idx];
        sG[idx] = s;
    }
    __syncthreads();
    if (tid < 64) sQ[tid] = sG[tid * 65];          // diagonal
    __syncthreads();
    if (tid < 64) {
        int i = tid;
        double emax = 0.0;
        for (int j = 0; j < 64; ++j) {
            if (j == i) continue;
            double dist = fmax(sQ[i] + sQ[j] - 2.0 * sG[i * 64 + j], 0.0);
            double e = 1.0 / (dist + 1e-10);
            emax = fmax(emax, e);
        }
        sEmax[i] = emax;
    }
    __syncthreads();
    const float* gb = gum + (size_t)b * 4096 * 2;
    float* ob = out + (size_t)b * 4096;
    for (int idx = tid; idx < 4096; idx += 256) {
        int i = idx >> 6, j = idx & 63;
        double p;
        if (i == j) {
            p = 0.99;
        } else {
            double dist = fmax(sQ[i] + sQ[j] - 2.0 * sG[idx], 0.0);
            double e = 1.0 / (dist + 1e-10);
            p = (e / sEmax[i]) * 0.99;
        }
        double l0 = log(p / (1.0 - p));
        double l1 = log((1.0 - p) / p);
        double y0 = l0 + (double)gb[idx * 2 + 0];
        double y1 = l1 + (double)gb[idx * 2 + 1];
        ob[idx] = (y0 >= y1) ? 1.0f : 0.0f;   // straight-through == one-hot exactly
    }
}

// ---------------- launcher ----------------
extern "C" void kernel_launch(void* const* d_in, const int* in_sizes, int n_in,
                              void* d_out, int out_size, void* d_ws, size_t ws_size,
                              hipStream_t stream) {
    const float* X  = (const float*)d_in[0];
    const float* A0 = (const float*)d_in[1];
    const float* A1 = (const float*)d_in[2];
    const float* A2 = (const float*)d_in[3];
    const float* fw = (const float*)d_in[4];
    const float* gm = (const float*)d_in[5];
    float* out = (float*)d_out;

    char* ws = (char*)d_ws;
    double2* tw  = (double2*)(ws);                 // 16 KB
    float*   XF  = (float*)(ws + 16384);           // 8,396,800 B
    double*  Y   = (double*)(ws + 8413184);        // 16,793,600 B
    // part aliases XF (dead after gemm): 32*8*4096*8 = 8,388,608 B
    double*  part = (double*)(ws + 16384);

    k_twiddle<<<4, 256, 0, stream>>>(tw);
    k_fft<<<Bn * Cn, 256, 0, stream>>>(X, tw, XF);
    k_gemm<<<dim3(64, 6, 3), 256, 0, stream>>>(XF, A0, A1, A2, Y);
    k_dist<<<dim3(Bn, 8), 256, 0, stream>>>(Y, fw, part);
    k_decide<<<Bn, 256, 0, stream>>>(part, gm, out);
}

// Round 4
// 189.340 us; speedup vs baseline: 2.0376x; 1.1479x over previous
//
#include <hip/hip_runtime.h>
#include <math.h>

#define Bn 32
#define Cn 64
#define Ln 2048
#define NFREQ 1025
#define S0c 341
#define S1c 341
#define S2c 343

#define PI_D 3.14159265358979323846

// padded LDS index: breaks power-of-2 stride bank conflicts
#define PADIX(i) ((i) + ((i) >> 4))

// ---------------- K1: twiddle table tw[t] = e^{-2 pi i t / 2048}, t<2048 ----------------
__global__ void k_twiddle(double2* __restrict__ tw) {
    int t = blockIdx.x * blockDim.x + threadIdx.x;
    if (t < 2048) {
        double ang = -2.0 * PI_D * (double)t / 2048.0;
        double s, c;
        sincos(ang, &s, &c);
        tw[t] = make_double2(c, s);
    }
}

// radix-4 digit reversal of a 10-bit index
__device__ __forceinline__ int rev4_10(unsigned x) {
    unsigned t = __brev(x) >> 22;                       // full 10-bit reversal
    return (int)(((t & 0x155u) << 1) | ((t >> 1) & 0x155u));  // un-reverse bit pairs
}

// ---------------- K2: packed-real rfft via 1024-pt radix-4 complex FFT + split ----------------
__global__ __launch_bounds__(256) void k_fft(const float* __restrict__ X,
                                             const double2* __restrict__ tw,
                                             float* __restrict__ XF) {
    __shared__ double re[1088];
    __shared__ double im[1088];
    int row = blockIdx.x;
    int tid = threadIdx.x;
    const float2* xr = (const float2*)(X + (size_t)row * Ln);
    for (int m = tid; m < 1024; m += 256) {
        float2 v = xr[m];
        re[PADIX(m)] = (double)v.x; im[PADIX(m)] = (double)v.y;  // z[m]=x[2m]+i x[2m+1]
    }
    __syncthreads();
    // 5 radix-4 DIF stages, 256 butterflies each (one per thread)
    #pragma unroll
    for (int s = 0; s < 5; ++s) {
        int log2Q = 8 - 2 * s;
        int Q = 1 << log2Q;
        int k = tid & (Q - 1);
        int g = tid >> log2Q;
        int base = (g << (log2Q + 2)) + k;
        int i0 = PADIX(base), i1 = PADIX(base + Q), i2 = PADIX(base + 2 * Q), i3 = PADIX(base + 3 * Q);
        double ar = re[i0], ai = im[i0];
        double br = re[i1], bi = im[i1];
        double cr = re[i2], ci = im[i2];
        double dr = re[i3], di = im[i3];
        int step = 2 << (2 * s);
        double2 w1 = tw[k * step];
        double2 w2 = tw[2 * k * step];
        double2 w3 = tw[3 * k * step];
        double t0r = ar + cr, t0i = ai + ci;
        double t1r = ar - cr, t1i = ai - ci;
        double t2r = br + dr, t2i = bi + di;
        double t3r = br - dr, t3i = bi - di;
        // y0 = t0 + t2
        re[i0] = t0r + t2r; im[i0] = t0i + t2i;
        // y1 = (t1 - i t3) * w1
        double u1r = t1r + t3i, u1i = t1i - t3r;
        re[i1] = u1r * w1.x - u1i * w1.y; im[i1] = u1r * w1.y + u1i * w1.x;
        // y2 = (t0 - t2) * w2
        double u2r = t0r - t2r, u2i = t0i - t2i;
        re[i2] = u2r * w2.x - u2i * w2.y; im[i2] = u2r * w2.y + u2i * w2.x;
        // y3 = (t1 + i t3) * w3
        double u3r = t1r - t3i, u3i = t1i + t3r;
        re[i3] = u3r * w3.x - u3i * w3.y; im[i3] = u3r * w3.y + u3i * w3.x;
        __syncthreads();
    }
    // split: X[k] = E_k + e^{-2pi i k/2048} O_k from Z (positions radix-4-digit-reversed)
    float* out = XF + (size_t)row * NFREQ;
    for (int k = tid; k <= 1024; k += 256) {
        double Xr, Xi;
        if (k == 0)        { Xr = re[0] + im[0]; Xi = 0.0; }
        else if (k == 1024){ Xr = re[0] - im[0]; Xi = 0.0; }
        else {
            int rv  = PADIX(rev4_10((unsigned)k));
            int rv2 = PADIX(rev4_10((unsigned)(1024 - k)));
            double Zr = re[rv],  Zi = im[rv];
            double Wr = re[rv2], Wi = im[rv2];
            double Er = 0.5 * (Zr + Wr), Ei = 0.5 * (Zi - Wi);
            double Or = 0.5 * (Zi + Wi), Oi = -0.5 * (Zr - Wr);
            double2 t = tw[k];
            Xr = Er + t.x * Or - t.y * Oi;
            Xi = Ei + t.x * Oi + t.y * Or;
        }
        out[k] = (float)sqrt(Xr * Xr + Xi * Xi);
    }
}

// ---------------- K3: fused 3-band GEMM, 64x64 tile, 4x4 micro, f64 LDS ----------------
// grid (32 row-tiles, 6 col-tiles, 3 bands); block 256 (16x16).
__global__ __launch_bounds__(256) void k_gemm(const float* __restrict__ XF,
                                              const float* __restrict__ A0,
                                              const float* __restrict__ A1,
                                              const float* __restrict__ A2,
                                              double* __restrict__ Y) {
    const int Sarr[3] = {S0c, S1c, S2c};
    const int Oarr[3] = {0, S0c, S0c + S1c};
    int z = blockIdx.z;
    const float* A = (z == 0) ? A0 : ((z == 1) ? A1 : A2);
    int S = Sarr[z], O = Oarr[z];

    __shared__ alignas(16) double sX[32][66];   // [k][row], 528B rows (16B-aligned)
    __shared__ alignas(16) double sA[32][66];   // [k][col]
    int r0 = blockIdx.x * 64;
    int d0 = blockIdx.y * 64;
    int tid = threadIdx.x;
    int tx = tid & 15, ty = tid >> 4;   // rows 4ty.., cols 4tx..
    int kl = tid & 31;                  // staging k-local (coalesced global)
    int rl = tid >> 5;                  // staging row/col base, stride 8

    auto load_tile = [&](int s0, float* px, float* pa) {
        int ss = s0 + kl;
        bool sv = ss < S;
        #pragma unroll
        for (int i = 0; i < 8; ++i)
            px[i] = sv ? XF[(size_t)(r0 + rl + 8 * i) * NFREQ + O + ss] : 0.0f;
        #pragma unroll
        for (int j = 0; j < 8; ++j) {
            int d = d0 + rl + 8 * j;
            pa[j] = (sv && d < S) ? A[(size_t)d * S + ss] : 0.0f;
        }
    };

    double acc[4][4] = {};
    float px[8], pa[8];
    load_tile(0, px, pa);
    int nsteps = (S + 31) / 32;
    for (int st = 0; st < nsteps; ++st) {
        __syncthreads();
        #pragma unroll
        for (int i = 0; i < 8; ++i) sX[kl][rl + 8 * i] = (double)px[i];
        #pragma unroll
        for (int j = 0; j < 8; ++j) sA[kl][rl + 8 * j] = (double)pa[j];
        __syncthreads();
        if (st + 1 < nsteps) load_tile((st + 1) * 32, px, pa);
        #pragma unroll
        for (int kk = 0; kk < 32; ++kk) {
            double2 x01 = *(const double2*)&sX[kk][4 * ty];
            double2 x23 = *(const double2*)&sX[kk][4 * ty + 2];
            double2 a01 = *(const double2*)&sA[kk][4 * tx];
            double2 a23 = *(const double2*)&sA[kk][4 * tx + 2];
            double xv[4] = {x01.x, x01.y, x23.x, x23.y};
            double av[4] = {a01.x, a01.y, a23.x, a23.y};
            #pragma unroll
            for (int i = 0; i < 4; ++i)
                #pragma unroll
                for (int j = 0; j < 4; ++j)
                    acc[i][j] = fma(xv[i], av[j], acc[i][j]);
        }
    }
    #pragma unroll
    for (int i = 0; i < 4; ++i) {
        int bc = r0 + 4 * ty + i;
        #pragma unroll
        for (int j = 0; j < 4; ++j) {
            int d = d0 + 4 * tx + j;
            if (d < S) Y[(size_t)bc * NFREQ + O + d] = acc[i][j];
        }
    }
}

// ---------------- K4: weighted Gram partials G = Yw Yw^T per (batch, dim-chunk) ----------------
__global__ __launch_bounds__(256) void k_dist(const double* __restrict__ Y,
                                              const float* __restrict__ fw,
                                              double* __restrict__ part) {
    __shared__ double sY[64][65];
    int b = blockIdx.x;
    int chunk = blockIdx.y;
    int dlo = chunk * 128;
    int dhi = (chunk == 7) ? NFREQ : dlo + 128;
    int tid = threadIdx.x;
    int tx = tid & 15, ty = tid >> 4;

    double f0 = (double)fw[0], f1 = (double)fw[1], f2 = (double)fw[2];
    double m = fmax(f0, fmax(f1, f2));
    double e0 = exp(f0 - m), e1 = exp(f1 - m), e2 = exp(f2 - m);
    double esum = e0 + e1 + e2;
    double sw0 = sqrt(e0 / esum), sw1 = sqrt(e1 / esum), sw2 = sqrt(e2 / esum);

    const double* Yb = Y + (size_t)b * Cn * NFREQ;
    double acc[4][4] = {};
    for (int d0 = dlo; d0 < dhi; d0 += 64) {
        for (int e = tid; e < 64 * 64; e += 256) {
            int r = e >> 6, c = e & 63;
            int d = d0 + c;
            double v = 0.0;
            if (d < dhi) {
                double sw = (d < S0c) ? sw0 : ((d < S0c + S1c) ? sw1 : sw2);
                v = Yb[(size_t)r * NFREQ + d] * sw;
            }
            sY[r][c] = v;
        }
        __syncthreads();
        #pragma unroll 8
        for (int kk = 0; kk < 64; ++kk) {
            double yi[4], yj[4];
            #pragma unroll
            for (int ii = 0; ii < 4; ++ii) yi[ii] = sY[16 * ii + ty][kk];
            #pragma unroll
            for (int jj = 0; jj < 4; ++jj) yj[jj] = sY[16 * jj + tx][kk];
            #pragma unroll
            for (int ii = 0; ii < 4; ++ii)
                #pragma unroll
                for (int jj = 0; jj < 4; ++jj)
                    acc[ii][jj] = fma(yi[ii], yj[jj], acc[ii][jj]);
        }
        __syncthreads();
    }
    double* pb = part + (((size_t)b * 8 + chunk) << 12);
    #pragma unroll
    for (int ii = 0; ii < 4; ++ii)
        #pragma unroll
        for (int jj = 0; jj < 4; ++jj)
            pb[(16 * ii + ty) * 64 + (16 * jj + tx)] = acc[ii][jj];
}

// ---------------- K5: sum Gram partials, dist = Gii+Gjj-2Gij, gumbel decision ----------------
// grid (32 batches, 16 row-groups); block 256 = 4 waves, one wave per matrix row.
__global__ __launch_bounds__(256) void k_decide(const double* __restrict__ part,
                                                const float* __restrict__ gum,
                                                float* __restrict__ out) {
    __shared__ double sQ[64];
    int b = blockIdx.x;
    int tid = threadIdx.x;
    const double* pb = part + (((size_t)b * 8) << 12);
    if (tid < 64) {
        double q = 0.0;
        #pragma unroll
        for (int c = 0; c < 8; ++c) q += pb[((size_t)c << 12) + tid * 65];
        sQ[tid] = q;
    }
    __syncthreads();
    int i = blockIdx.y * 4 + (tid >> 6);
    int j = tid & 63;
    double g = 0.0;
    #pragma unroll
    for (int c = 0; c < 8; ++c) g += pb[((size_t)c << 12) + i * 64 + j];
    double dist = fmax(sQ[i] + sQ[j] - 2.0 * g, 0.0);
    double e = (i == j) ? 0.0 : 1.0 / (dist + 1e-10);
    double emax = e;
    #pragma unroll
    for (int off = 32; off; off >>= 1)
        emax = fmax(emax, __shfl_xor(emax, off, 64));
    double p = (i == j) ? 0.99 : (e / emax) * 0.99;
    double l0 = log(p / (1.0 - p));
    double l1 = log((1.0 - p) / p);
    int idx = i * 64 + j;
    const float* gb = gum + (size_t)b * 8192;
    double y0 = l0 + (double)gb[2 * idx];
    double y1 = l1 + (double)gb[2 * idx + 1];
    out[(size_t)b * 4096 + idx] = (y0 >= y1) ? 1.0f : 0.0f;  // ST == one-hot exactly
}

// ---------------- launcher ----------------
extern "C" void kernel_launch(void* const* d_in, const int* in_sizes, int n_in,
                              void* d_out, int out_size, void* d_ws, size_t ws_size,
                              hipStream_t stream) {
    const float* X  = (const float*)d_in[0];
    const float* A0 = (const float*)d_in[1];
    const float* A1 = (const float*)d_in[2];
    const float* A2 = (const float*)d_in[3];
    const float* fw = (const float*)d_in[4];
    const float* gm = (const float*)d_in[5];
    float* out = (float*)d_out;

    char* ws = (char*)d_ws;
    double2* tw  = (double2*)(ws);                 // 2048*16 = 32,768 B
    float*   XF  = (float*)(ws + 32768);           // 8,396,800 B
    double*  Y   = (double*)(ws + 8429568);        // 16,793,600 B (ends 25,223,168)
    // part aliases XF (dead after gemm): 32*8*4096*8 = 8,388,608 B
    double*  part = (double*)(ws + 32768);

    k_twiddle<<<8, 256, 0, stream>>>(tw);
    k_fft<<<Bn * Cn, 256, 0, stream>>>(X, tw, XF);
    k_gemm<<<dim3(32, 6, 3), 256, 0, stream>>>(XF, A0, A1, A2, Y);
    k_dist<<<dim3(Bn, 8), 256, 0, stream>>>(Y, fw, part);
    k_decide<<<dim3(Bn, 16), 256, 0, stream>>>(part, gm, out);
}